// Round 14
// baseline (50.508 us; speedup 1.0000x reference)
//
#include <hip/hip_runtime.h>

// SimpleHybridModel via MFMA, all-transposed chaining:
//  conv1d(k=3,SAME,relu) -> SimpleRNN(16,tanh) -> dense(8,relu) -> dense(1)
//
// R14 changes vs R12/R13 (kill the L1 transaction storm):
//  - Cross-round analysis: wave lifetime ~13us (33k cy) in R11-R13, >>
//    instruction model. Cause: per-lane-scattered VMEM. R12/R13 staging
//    (float2 @ 280B lane stride) touches each 64B line ~8x -> ~18M L1
//    requests. Weight fragments add ~350 divergent line-touches per wave.
//  - x staging: tid-linear float4 (each line touched ONCE, R5's pattern) +
//    magic-div (elem,row,col) + 4x ds_write_b16 (alignment/straddle-proof).
//  - weights: coalesced into LDS once per block; fragment gathers hit LDS
//    banks instead of L1.
//  - 64 elems/block, 1 chain/lane: tile 21.5KB + wg 4.1KB = 25.6KB ->
//    6 blocks/CU = 24 waves (75% cap); __launch_bounds__(256,5).
// Retained: 21-slot shared-pad layout (zero masking, aligned b128 reads),
// phase split (full unroll), conv bias rides MFMA k=31 vs dummy-1.0 half,
// 2*log2e folded into A2/AU/rnn_b, rcp-tanh, head via MFMA.

#define BLK 256
#define LSEQ 20
#define EPB 64    // elements per block
#define EPW 84    // dwords per element: 21 slots * 4
#define LOG2E2 2.8853900817779268f

// weight LDS offsets (floats)
#define W_CONV   0
#define W_CONVB  336
#define W_RNNW   352
#define W_RNNU   608
#define W_RNNB   864
#define W_D1W    880
#define W_D1B    1008
#define W_OUTW   1016
#define W_OUTB   1024

typedef _Float16 f16;
typedef __fp16   fp16x2 __attribute__((ext_vector_type(2)));
typedef _Float16 f16x4 __attribute__((ext_vector_type(4)));
typedef _Float16 f16x8 __attribute__((ext_vector_type(8)));
typedef float    f32x4 __attribute__((ext_vector_type(4)));

union UB128 { uint4 q; f16x8 v; };
union UB64  { f16x4 v; fp16x2 p[2]; };

__global__ __launch_bounds__(BLK, 5) void hybrid_fwd(
    const float* __restrict__ x,
    const float* __restrict__ conv_w, const float* __restrict__ conv_b,
    const float* __restrict__ rnn_w,  const float* __restrict__ rnn_u,
    const float* __restrict__ rnn_b,
    const float* __restrict__ d1_w,   const float* __restrict__ d1_b,
    const float* __restrict__ out_w,  const float* __restrict__ out_b,
    float* __restrict__ out)
{
    __shared__ __align__(16) uint  xs[EPB * EPW + 8];   // 21536 B
    __shared__ float wg[1025];                           // 4100 B

    const int tid  = threadIdx.x;
    const int wave = tid >> 6, lane = tid & 63;
    const int b16  = lane & 15, g = lane >> 4;
    const long BE  = (long)blockIdx.x * EPB;

    // ---- pad rows (slot 0 of each element) + 2 guard rows: (0..0, 1.0h) ----
    const uint4 PAD = make_uint4(0u, 0u, 0u, 0x3C000000u);
    if (tid < EPB) *(uint4*)(xs + tid * EPW) = PAD;
    if (tid < 2)   *(uint4*)(xs + EPB * EPW + 4 * tid) = PAD;
    // ---- dummy 1.0 at half#7 of slots 1..20 (64*20 = 1280 = 5 rounds) ----
    #pragma unroll
    for (int k = 0; k < 5; ++k) {
        int t = tid + k * BLK;
        int e = t / 20, s = t - e * 20;              // slot s+1
        *(f16*)((char*)(xs + e * EPW) + (s + 1) * 16 + 14) = (f16)1.0f;
    }
    // ---- stage x: tid-linear float4 (each 64B line touched once) ----
    const float4* xsrc = (const float4*)(x + BE * 140);
    #pragma unroll
    for (int k = 0; k < 9; ++k) {
        int g4 = tid + k * BLK;                      // 2240 float4 total
        if (g4 < 2240) {
            float4 v = xsrc[g4];
            int e = g4 / 35, j = g4 - e * 35;
            int p = 4 * j;                           // flat float index 0..136
            int r = p / 7, c = p - 7 * r;
            char* eb = (char*)(xs + e * EPW);
            *(f16*)(eb + (r + 1) * 16 + 2 * c) = (f16)v.x;
            if (++c == 7) { c = 0; ++r; }
            *(f16*)(eb + (r + 1) * 16 + 2 * c) = (f16)v.y;
            if (++c == 7) { c = 0; ++r; }
            *(f16*)(eb + (r + 1) * 16 + 2 * c) = (f16)v.z;
            if (++c == 7) { c = 0; ++r; }
            *(f16*)(eb + (r + 1) * 16 + 2 * c) = (f16)v.w;
        }
    }
    // ---- stage weights (coalesced; fragment builds gather from LDS) ----
    wg[W_RNNW + tid] = rnn_w[tid];
    {
        int i = tid;
        if (i < 336) wg[W_CONV + i] = conv_w[i];
        i = tid - 336;                               // reuse upper threads
        if (i >= 0 && i < 256) { /* covered below */ }
    }
    if (tid < 80) wg[W_CONV + 256 + tid] = conv_w[256 + tid];   // 336 = 256+80
    if (tid < 256) { /* rnn_u */ }
    wg[W_RNNU + tid] = rnn_u[tid];
    if (tid < 16)  wg[W_CONVB + tid] = conv_b[tid];
    if (tid < 16)  wg[W_RNNB + tid]  = rnn_b[tid];
    if (tid < 128) wg[W_D1W + tid]   = d1_w[tid];
    if (tid < 8)   { wg[W_D1B + tid] = d1_b[tid]; wg[W_OUTW + tid] = out_w[tid]; }
    if (tid == 0)  wg[W_OUTB] = out_b[0];
    if (tid < 256) { int i = tid; if (i < 256) wg[W_CONV + (i < 256 ? i : 0)] = conv_w[i < 256 ? i : 0]; }

    __syncthreads();

    // ---- fragments from LDS (banked gathers, no L1) ----
    f16x8 A1;
    #pragma unroll
    for (int t = 0; t < 8; ++t) {
        float wv = wg[W_CONV + min(g * 7 + t, 20) * 16 + b16];
        float sel = (g < 3 && t < 7) ? wv
                  : ((g == 3 && t == 7) ? wg[W_CONVB + b16] : 0.f);
        A1[t] = (f16)sel;
    }
    f16x4 A2, AU;
    f32x4 rbp;
    #pragma unroll
    for (int t = 0; t < 4; ++t) {
        A2[t]  = (f16)(LOG2E2 * wg[W_RNNW + (4 * g + t) * 16 + b16]);
        AU[t]  = (f16)(LOG2E2 * wg[W_RNNU + (4 * g + t) * 16 + b16]);
        rbp[t] = LOG2E2 * wg[W_RNNB + 4 * g + t];
    }
    f16x4 A3;
    f32x4 c3;
    #pragma unroll
    for (int t = 0; t < 4; ++t) {
        int j = 4 * g + t;
        A3[t] = (f16)(b16 < 8 ? wg[W_D1W + j * 8 + b16] : 0.f);
        c3[t] = wg[W_D1B + min(j, 7)];
    }
    float ow[4];
    #pragma unroll
    for (int r = 0; r < 4; ++r)
        ow[r] = (g < 2) ? wg[W_OUTW + min(4 * g + r, 7)] : 0.f;
    const float ob = wg[W_OUTB];
    const f32x4 zero4 = {0.f, 0.f, 0.f, 0.f};

    // per-lane read base; step l reads slot l+g -> one aligned b128
    const uint* rb0 = xs + (wave * 16 + b16) * EPW + 4 * g;

    // ---- Phase A: conv + relu, full unroll (B2s static-indexed) ----
    f16x4 B2s[LSEQ];
    #pragma unroll
    for (int l = 0; l < LSEQ; ++l) {
        UB128 B1;
        B1.q = *(const uint4*)(rb0 + 4 * l);
        f32x4 a1 = __builtin_amdgcn_mfma_f32_16x16x32_f16(A1, B1.v, zero4, 0, 0, 0);
        UB64 B2;
        B2.p[0] = __builtin_amdgcn_cvt_pkrtz(fmaxf(a1[0], 0.f), fmaxf(a1[1], 0.f));
        B2.p[1] = __builtin_amdgcn_cvt_pkrtz(fmaxf(a1[2], 0.f), fmaxf(a1[3], 0.f));
        B2s[l] = B2.v;
    }
    // ---- Phase B: serial recurrence ----
    f16x4 H = {};
    #pragma unroll
    for (int l = 0; l < LSEQ; ++l) {
        f32x4 a2 = __builtin_amdgcn_mfma_f32_16x16x16f16(A2, B2s[l], rbp, 0, 0, 0);
        a2 = __builtin_amdgcn_mfma_f32_16x16x16f16(AU, H, a2, 0, 0, 0);
        float t0 = __builtin_amdgcn_rcpf(1.f + __builtin_amdgcn_exp2f(a2[0]));
        float t1 = __builtin_amdgcn_rcpf(1.f + __builtin_amdgcn_exp2f(a2[1]));
        float t2 = __builtin_amdgcn_rcpf(1.f + __builtin_amdgcn_exp2f(a2[2]));
        float t3 = __builtin_amdgcn_rcpf(1.f + __builtin_amdgcn_exp2f(a2[3]));
        UB64 Hn;
        Hn.p[0] = __builtin_amdgcn_cvt_pkrtz(fmaf(-2.f, t0, 1.f), fmaf(-2.f, t1, 1.f));
        Hn.p[1] = __builtin_amdgcn_cvt_pkrtz(fmaf(-2.f, t2, 1.f), fmaf(-2.f, t3, 1.f));
        H = Hn.v;
    }
    // ---- head via MFMA ----
    f32x4 a3 = __builtin_amdgcn_mfma_f32_16x16x16f16(A3, H, c3, 0, 0, 0);
    float part = 0.f;
    #pragma unroll
    for (int r = 0; r < 4; ++r)
        part = fmaf(fmaxf(a3[r], 0.f), ow[r], part);
    part += __shfl_xor(part, 16);
    part += __shfl_xor(part, 32);
    if (lane < 16)
        out[BE + wave * 16 + lane] = part + ob;
}

extern "C" void kernel_launch(void* const* d_in, const int* in_sizes, int n_in,
                              void* d_out, int out_size, void* d_ws, size_t ws_size,
                              hipStream_t stream) {
    const float* x      = (const float*)d_in[0];
    const float* conv_w = (const float*)d_in[1];
    const float* conv_b = (const float*)d_in[2];
    const float* rnn_w  = (const float*)d_in[3];
    const float* rnn_u  = (const float*)d_in[4];
    const float* rnn_b  = (const float*)d_in[5];
    const float* d1_w   = (const float*)d_in[6];
    const float* d1_b   = (const float*)d_in[7];
    const float* out_w  = (const float*)d_in[8];
    const float* out_b  = (const float*)d_in[9];
    float* out = (float*)d_out;

    const int B = out_size;                 // 262144
    const int grid = B / EPB;               // 4096 blocks
    hybrid_fwd<<<grid, BLK, 0, stream>>>(x, conv_w, conv_b, rnn_w, rnn_u, rnn_b,
                                         d1_w, d1_b, out_w, out_b, out);
}

// Round 15
// 45.366 us; speedup vs baseline: 1.1133x; 1.1133x over previous
//
#include <hip/hip_runtime.h>

// SimpleHybridModel via MFMA, all-transposed chaining:
//  conv1d(k=3,SAME,relu) -> SimpleRNN(16,tanh) -> dense(8,relu) -> dense(1)
//
// R15: multi-tile pipelined blocks (amortize + overlap per-block fixed cost).
// Evidence: R12 best (43.6us, occ 29.5%); R13/R14 raised occupancy, LOST time
// -> limiter is per-block fixed latency (weight loads, staging latency,
// barrier), not wave slots. So: 1024 blocks x 4 tiles each, ping-pong f16
// tiles; per tile: issue t+1 loads (9 float4/thread, tid-linear: each 64B
// line touched once) -> compute tile t (~2k cy, hides HBM latency) ->
// vmcnt(0) -> scatter-convert t+1 -> barrier. Weights/pads paid once per block.
// Retained from R12/R13: 21-slot f16 tile (slot0 = shared pad row
// (0..0,1.0h), slot s=l+g read as ONE aligned ds_read_b128; cross-element
// reads land on pads/zero-A1 taps), conv bias rides MFMA k=31 vs dummy-1.0
// half, 2*log2e folded into A2/AU/rnn_b, rcp+exp2 tanh, packed cvts,
// head via MFMA.

#define BLK 256
#define LSEQ 20
#define EPB 64            // elements per tile
#define EPW 84            // dwords per element: 21 slots * 4
#define TILE_DW (EPB*EPW + 8)   // 5384 dwords (2 guard slots)
#define NT 4              // tiles per block
#define LOG2E2 2.8853900817779268f

typedef _Float16 f16;
typedef __fp16   fp16x2 __attribute__((ext_vector_type(2)));
typedef _Float16 f16x4 __attribute__((ext_vector_type(4)));
typedef _Float16 f16x8 __attribute__((ext_vector_type(8)));
typedef float    f32x4 __attribute__((ext_vector_type(4)));

union UB128 { uint4 q; f16x8 v; };
union UB64  { f16x4 v; fp16x2 p[2]; };

__device__ __forceinline__ void issue_loads(const float4* __restrict__ xsrc,
                                            int tid, float4 (&v)[9]) {
    #pragma unroll
    for (int k = 0; k < 9; ++k) {
        int g4 = tid + k * BLK;
        if (g4 < 2240) v[k] = xsrc[g4];
    }
}

__device__ __forceinline__ void write_tile(uint* tile, int tid,
                                           const float4 (&v)[9]) {
    #pragma unroll
    for (int k = 0; k < 9; ++k) {
        int g4 = tid + k * BLK;
        if (g4 < 2240) {
            int e = g4 / 35, j = g4 - e * 35;
            int p = 4 * j;
            int r = p / 7, c = p - 7 * r;
            char* eb = (char*)(tile + e * EPW);
            *(f16*)(eb + (r + 1) * 16 + 2 * c) = (f16)v[k].x;
            if (++c == 7) { c = 0; ++r; }
            *(f16*)(eb + (r + 1) * 16 + 2 * c) = (f16)v[k].y;
            if (++c == 7) { c = 0; ++r; }
            *(f16*)(eb + (r + 1) * 16 + 2 * c) = (f16)v[k].z;
            if (++c == 7) { c = 0; ++r; }
            *(f16*)(eb + (r + 1) * 16 + 2 * c) = (f16)v[k].w;
        }
    }
}

__global__ __launch_bounds__(BLK, 3) void hybrid_fwd(
    const float* __restrict__ x,
    const float* __restrict__ conv_w, const float* __restrict__ conv_b,
    const float* __restrict__ rnn_w,  const float* __restrict__ rnn_u,
    const float* __restrict__ rnn_b,
    const float* __restrict__ d1_w,   const float* __restrict__ d1_b,
    const float* __restrict__ out_w,  const float* __restrict__ out_b,
    float* __restrict__ out)
{
    __shared__ __align__(16) uint xs[2][TILE_DW];   // 43072 B

    const int tid  = threadIdx.x;
    const int wave = tid >> 6, lane = tid & 63;
    const int b16  = lane & 15, g = lane >> 4;
    const long blockElem = (long)blockIdx.x * (EPB * NT);

    // ---- one-time pad/dummy init for BOTH tile buffers ----
    const uint4 PAD = make_uint4(0u, 0u, 0u, 0x3C000000u);
    #pragma unroll
    for (int b = 0; b < 2; ++b) {
        if (tid < EPB) *(uint4*)(xs[b] + tid * EPW) = PAD;      // slot 0
        if (tid < 2)   *(uint4*)(xs[b] + EPB * EPW + 4 * tid) = PAD;  // guards
        #pragma unroll
        for (int k = 0; k < 5; ++k) {                            // dummy 1.0
            int t = tid + k * BLK;                               // 1280
            int e = t / 20, s = t - e * 20;
            *(f16*)((char*)(xs[b] + e * EPW) + (s + 1) * 16 + 14) = (f16)1.0f;
        }
    }

    // ---- weight fragments, once per block (global, uniform-ish offsets) ----
    f16x8 A1;
    #pragma unroll
    for (int t = 0; t < 8; ++t) {
        float wv = conv_w[min(g * 7 + t, 20) * 16 + b16];
        float sel = (g < 3 && t < 7) ? wv
                  : ((g == 3 && t == 7) ? conv_b[b16] : 0.f);
        A1[t] = (f16)sel;
    }
    f16x4 A2, AU;
    f32x4 rbp;
    #pragma unroll
    for (int t = 0; t < 4; ++t) {
        A2[t]  = (f16)(LOG2E2 * rnn_w[(4 * g + t) * 16 + b16]);
        AU[t]  = (f16)(LOG2E2 * rnn_u[(4 * g + t) * 16 + b16]);
        rbp[t] = LOG2E2 * rnn_b[4 * g + t];
    }
    f16x4 A3;
    f32x4 c3;
    #pragma unroll
    for (int t = 0; t < 4; ++t) {
        int j = 4 * g + t;
        A3[t] = (f16)(b16 < 8 ? d1_w[j * 8 + b16] : 0.f);
        c3[t] = d1_b[min(j, 7)];
    }
    float ow[4];
    #pragma unroll
    for (int r = 0; r < 4; ++r)
        ow[r] = (g < 2) ? out_w[min(4 * g + r, 7)] : 0.f;
    const float ob = out_b[0];
    const f32x4 zero4 = {0.f, 0.f, 0.f, 0.f};

    // ---- prologue: stage tile 0 ----
    float4 v[9];
    issue_loads((const float4*)(x + blockElem * 140), tid, v);
    write_tile(xs[0], tid, v);
    __syncthreads();

    // ---- pipelined tile loop ----
    #pragma unroll
    for (int t = 0; t < NT; ++t) {
        if (t < NT - 1)   // issue next tile's loads; latency hides under compute
            issue_loads((const float4*)(x + (blockElem + (t + 1) * EPB) * 140), tid, v);

        // ---- compute tile t ----
        const uint* rb0 = xs[t & 1] + (wave * 16 + b16) * EPW + 4 * g;
        f16x4 H = {};
        #pragma unroll
        for (int l = 0; l < LSEQ; ++l) {
            UB128 B1;
            B1.q = *(const uint4*)(rb0 + 4 * l);
            f32x4 a1 = __builtin_amdgcn_mfma_f32_16x16x32_f16(A1, B1.v, zero4, 0, 0, 0);
            UB64 B2;
            B2.p[0] = __builtin_amdgcn_cvt_pkrtz(fmaxf(a1[0], 0.f), fmaxf(a1[1], 0.f));
            B2.p[1] = __builtin_amdgcn_cvt_pkrtz(fmaxf(a1[2], 0.f), fmaxf(a1[3], 0.f));
            f32x4 a2 = __builtin_amdgcn_mfma_f32_16x16x16f16(A2, B2.v, rbp, 0, 0, 0);
            a2 = __builtin_amdgcn_mfma_f32_16x16x16f16(AU, H, a2, 0, 0, 0);
            float t0 = __builtin_amdgcn_rcpf(1.f + __builtin_amdgcn_exp2f(a2[0]));
            float t1 = __builtin_amdgcn_rcpf(1.f + __builtin_amdgcn_exp2f(a2[1]));
            float t2 = __builtin_amdgcn_rcpf(1.f + __builtin_amdgcn_exp2f(a2[2]));
            float t3 = __builtin_amdgcn_rcpf(1.f + __builtin_amdgcn_exp2f(a2[3]));
            UB64 Hn;
            Hn.p[0] = __builtin_amdgcn_cvt_pkrtz(fmaf(-2.f, t0, 1.f), fmaf(-2.f, t1, 1.f));
            Hn.p[1] = __builtin_amdgcn_cvt_pkrtz(fmaf(-2.f, t2, 1.f), fmaf(-2.f, t3, 1.f));
            H = Hn.v;
        }
        f32x4 a3 = __builtin_amdgcn_mfma_f32_16x16x16f16(A3, H, c3, 0, 0, 0);
        float part = 0.f;
        #pragma unroll
        for (int r = 0; r < 4; ++r)
            part = fmaf(fmaxf(a3[r], 0.f), ow[r], part);
        part += __shfl_xor(part, 16);
        part += __shfl_xor(part, 32);
        if (lane < 16)
            out[blockElem + t * EPB + wave * 16 + b16] = part + ob;

        // ---- convert+write next tile (loads have arrived under compute) ----
        if (t < NT - 1) {
            write_tile(xs[(t + 1) & 1], tid, v);
            __syncthreads();
        }
    }
}

extern "C" void kernel_launch(void* const* d_in, const int* in_sizes, int n_in,
                              void* d_out, int out_size, void* d_ws, size_t ws_size,
                              hipStream_t stream) {
    const float* x      = (const float*)d_in[0];
    const float* conv_w = (const float*)d_in[1];
    const float* conv_b = (const float*)d_in[2];
    const float* rnn_w  = (const float*)d_in[3];
    const float* rnn_u  = (const float*)d_in[4];
    const float* rnn_b  = (const float*)d_in[5];
    const float* d1_w   = (const float*)d_in[6];
    const float* d1_b   = (const float*)d_in[7];
    const float* out_w  = (const float*)d_in[8];
    const float* out_b  = (const float*)d_in[9];
    float* out = (float*)d_out;

    const int B = out_size;                 // 262144
    const int grid = B / (EPB * NT);        // 1024 blocks x 4 tiles
    hybrid_fwd<<<grid, BLK, 0, stream>>>(x, conv_w, conv_b, rnn_w, rnn_u, rnn_b,
                                         d1_w, d1_b, out_w, out_b, out);
}